// Round 1
// baseline (259.629 us; speedup 1.0000x reference)
//
#include <hip/hip_runtime.h>
#include <hip/hip_bf16.h>

// out[b,s,o] = sum_i x[b,s,i] * (W[o,i]*scale) + bias[o]
// M = 2*512 = 1024, K = 4096, N = 11008. fp32 in/out, W stored int32 (int8-valued).
// bf16 MFMA: W int8 values are EXACT in bf16; x->bf16 loses <=2^-9 rel (ok vs thr 9.96).

#define M_TOT 1024
#define N_TOT 11008
#define K_TOT 4096
#define BM 128
#define BN 128
#define BK 64
#define NT (K_TOT / BK)  // 64 K-steps

typedef __attribute__((ext_vector_type(8))) short short8;   // 8 bf16 = 4 VGPR (MFMA A/B frag)
typedef __attribute__((ext_vector_type(4))) float f32x4;    // MFMA C/D frag

__device__ __forceinline__ unsigned short f2bf(float f) {
    __hip_bfloat16 h = __float2bfloat16(f);  // RNE
    return __builtin_bit_cast(unsigned short, h);
}

__device__ __forceinline__ unsigned long long pack4(float a, float b, float c, float d) {
    unsigned long long r = (unsigned long long)f2bf(a)
                         | ((unsigned long long)f2bf(b) << 16)
                         | ((unsigned long long)f2bf(c) << 32)
                         | ((unsigned long long)f2bf(d) << 48);
    return r;
}

__global__ __launch_bounds__(256, 2)
void otf_linear_kernel(const float* __restrict__ X,       // [1024, 4096]
                       const int* __restrict__ W,         // [11008, 4096] int8-valued
                       const float* __restrict__ scale,   // [1]
                       const float* __restrict__ bias,    // [11008]
                       float* __restrict__ out) {         // [1024, 11008]
    // LDS tiles, bf16, row stride 128 bytes, XOR-swizzled: byte ^= (row&7)<<4
    __shared__ __align__(16) unsigned char AsB[BM * BK * 2];  // 16 KB
    __shared__ __align__(16) unsigned char BsB[BN * BK * 2];  // 16 KB

    const int tid  = threadIdx.x;          // 0..255
    const int lane = tid & 63;
    const int wid  = tid >> 6;             // 0..3
    const int wr   = wid >> 1;             // wave row (0..1), 64-row sub-tile
    const int wc   = wid & 1;              // wave col (0..1), 64-col sub-tile
    const int lr   = lane & 15;            // row-in-16 (A) / col-in-16 (B)
    const int kb   = lane >> 4;            // k-block 0..3 (8 bf16 each)

    const int brow = blockIdx.y * BM;
    const int bcol = blockIdx.x * BN;

    // staging decomposition: 16 float4/int4 per 64-elem row -> 16 threads/row,
    // 16 rows per pass, 8 passes for 128 rows.
    const int srow = tid >> 4;             // 0..15 row-in-pass
    const int sc4  = tid & 15;             // 16B-group in row

    f32x4 areg[8];
    int4  breg[8];

    auto load_tiles = [&](int t) {
        const int k0 = t * BK;
#pragma unroll
        for (int p = 0; p < 8; ++p) {
            int row = p * 16 + srow;
            areg[p] = *(const f32x4*)(&X[(size_t)(brow + row) * K_TOT + k0 + sc4 * 4]);
            breg[p] = *(const int4*)(&W[(size_t)(bcol + row) * K_TOT + k0 + sc4 * 4]);
        }
    };

    auto store_tiles = [&]() {
#pragma unroll
        for (int p = 0; p < 8; ++p) {
            int row = p * 16 + srow;
            int boff = (sc4 * 8) ^ ((row & 7) << 4);
            *(unsigned long long*)(&AsB[row * 128 + boff]) =
                pack4(areg[p][0], areg[p][1], areg[p][2], areg[p][3]);
            *(unsigned long long*)(&BsB[row * 128 + boff]) =
                pack4((float)breg[p].x, (float)breg[p].y, (float)breg[p].z, (float)breg[p].w);
        }
    };

    f32x4 acc[4][4];
#pragma unroll
    for (int m = 0; m < 4; ++m)
#pragma unroll
        for (int n = 0; n < 4; ++n)
#pragma unroll
            for (int i = 0; i < 4; ++i) acc[m][n][i] = 0.0f;

    load_tiles(0);

    for (int t = 0; t < NT; ++t) {
        store_tiles();
        __syncthreads();
        if (t + 1 < NT) load_tiles(t + 1);   // prefetch next tile into regs; hidden under MFMA
#pragma unroll
        for (int kk = 0; kk < 2; ++kk) {     // two K=32 sub-steps
            short8 af[4], bf[4];
#pragma unroll
            for (int m = 0; m < 4; ++m) {
                int row = wr * 64 + m * 16 + lr;
                int col = (kk * 64 + kb * 16) ^ ((row & 7) << 4);
                af[m] = *(const short8*)(&AsB[row * 128 + col]);
            }
#pragma unroll
            for (int n = 0; n < 4; ++n) {
                int row = wc * 64 + n * 16 + lr;
                int col = (kk * 64 + kb * 16) ^ ((row & 7) << 4);
                bf[n] = *(const short8*)(&BsB[row * 128 + col]);
            }
#pragma unroll
            for (int m = 0; m < 4; ++m)
#pragma unroll
                for (int n = 0; n < 4; ++n)
                    acc[m][n] = __builtin_amdgcn_mfma_f32_16x16x32_bf16(af[m], bf[n], acc[m][n], 0, 0, 0);
        }
        __syncthreads();
    }

    // epilogue: out = acc * scale + bias
    const float sc = scale[0];
    const int orow0 = brow + wr * 64;
    const int ocol0 = bcol + wc * 64;
    float bv[4];
#pragma unroll
    for (int n = 0; n < 4; ++n) bv[n] = bias[ocol0 + n * 16 + lr];
#pragma unroll
    for (int m = 0; m < 4; ++m) {
#pragma unroll
        for (int i = 0; i < 4; ++i) {
            int r = orow0 + m * 16 + kb * 4 + i;   // C/D row = (lane>>4)*4 + reg
            size_t base = (size_t)r * N_TOT + ocol0;
#pragma unroll
            for (int n = 0; n < 4; ++n)
                out[base + n * 16 + lr] = acc[m][n][i] * sc + bv[n];
        }
    }
}

extern "C" void kernel_launch(void* const* d_in, const int* in_sizes, int n_in,
                              void* d_out, int out_size, void* d_ws, size_t ws_size,
                              hipStream_t stream) {
    const float* x     = (const float*)d_in[0];
    const int*   w     = (const int*)d_in[1];
    const float* scale = (const float*)d_in[2];
    const float* bias  = (const float*)d_in[3];
    float* out = (float*)d_out;

    dim3 grid(N_TOT / BN, M_TOT / BM);   // (86, 8) = 688 blocks
    otf_linear_kernel<<<grid, dim3(256), 0, stream>>>(x, w, scale, bias, out);
}

// Round 2
// 178.745 us; speedup vs baseline: 1.4525x; 1.4525x over previous
//
#include <hip/hip_runtime.h>
#include <hip/hip_bf16.h>

// out[m,o] = sum_k x[m,k] * (W[o,k]*scale) + bias[o]
// M=1024, K=4096, N=11008. Plan: pre-pass converts W(int32)->bf16 and X(f32)->bf16
// into d_ws; main GEMM is the m97 structure (128x128 tile, BK=64, global_load_lds
// width-16, single-buffered LDS, 4 waves 2x2, mfma_f32_16x16x32_bf16).

#define M_TOT 1024
#define N_TOT 11008
#define K_TOT 4096
#define BM 128
#define BN 128
#define BK 64
#define NT (K_TOT / BK)

typedef __attribute__((ext_vector_type(8))) short short8;   // 8 bf16
typedef __attribute__((ext_vector_type(4))) float f32x4;

__device__ __forceinline__ unsigned short f2bf(float f) {
    __hip_bfloat16 h = __float2bfloat16(f);  // RNE
    return __builtin_bit_cast(unsigned short, h);
}

__device__ __forceinline__ void gload16(const void* g, void* l) {
    __builtin_amdgcn_global_load_lds(
        (const __attribute__((address_space(1))) unsigned int*)g,
        (__attribute__((address_space(3))) unsigned int*)l,
        16, 0, 0);
}

// ---------------- pre-pass: W int32 -> bf16 (exact: |v|<=127) ----------------
__global__ void conv_w_kernel(const int* __restrict__ W,
                              __hip_bfloat16* __restrict__ Wb, int n8) {
    int idx = blockIdx.x * blockDim.x + threadIdx.x;
    int stride = gridDim.x * blockDim.x;
    for (int i = idx; i < n8; i += stride) {
        const int4* p = (const int4*)W + (size_t)i * 2;
        int4 a = p[0], b = p[1];
        short8 o;
        o[0] = (short)f2bf((float)a.x);
        o[1] = (short)f2bf((float)a.y);
        o[2] = (short)f2bf((float)a.z);
        o[3] = (short)f2bf((float)a.w);
        o[4] = (short)f2bf((float)b.x);
        o[5] = (short)f2bf((float)b.y);
        o[6] = (short)f2bf((float)b.z);
        o[7] = (short)f2bf((float)b.w);
        *(short8*)(Wb + (size_t)i * 8) = o;
    }
}

// ---------------- pre-pass: X f32 -> bf16 ----------------
__global__ void conv_x_kernel(const float* __restrict__ X,
                              __hip_bfloat16* __restrict__ Xb, int n8) {
    int idx = blockIdx.x * blockDim.x + threadIdx.x;
    int stride = gridDim.x * blockDim.x;
    for (int i = idx; i < n8; i += stride) {
        const f32x4* p = (const f32x4*)X + (size_t)i * 2;
        f32x4 a = p[0], b = p[1];
        short8 o;
        o[0] = (short)f2bf(a[0]);
        o[1] = (short)f2bf(a[1]);
        o[2] = (short)f2bf(a[2]);
        o[3] = (short)f2bf(a[3]);
        o[4] = (short)f2bf(b[0]);
        o[5] = (short)f2bf(b[1]);
        o[6] = (short)f2bf(b[2]);
        o[7] = (short)f2bf(b[3]);
        *(short8*)(Xb + (size_t)i * 8) = o;
    }
}

// ---------------- main GEMM: bf16 NT, m97 structure ----------------
__global__ __launch_bounds__(256, 2)
void gemm_bf16_kernel(const __hip_bfloat16* __restrict__ Xb,   // [1024,4096]
                      const __hip_bfloat16* __restrict__ Wb,   // [11008,4096]
                      const float* __restrict__ scale,
                      const float* __restrict__ bias,
                      float* __restrict__ out) {               // [1024,11008]
    __shared__ __align__(16) __hip_bfloat16 As[BM * BK];  // [128][64], linear
    __shared__ __align__(16) __hip_bfloat16 Bs[BN * BK];

    const int tid  = threadIdx.x;
    const int lane = tid & 63;
    const int wid  = tid >> 6;       // 0..3
    const int wr   = wid >> 1;
    const int wc   = wid & 1;
    const int lr   = lane & 15;
    const int kb   = lane >> 4;      // 0..3

    const int brow = blockIdx.y * BM;
    const int bcol = blockIdx.x * BN;

    // global_load_lds decomposition: 1 KB per instruction (64 lanes x 16B),
    // per wave 4 instrs each for A and B. Lane l covers row l>>3, col (l&7)*8
    // within its 8-row chunk.
    const int g_row = wid * 32 + (lane >> 3);   // + i*8 per instruction
    const int g_col = (lane & 7) * 8;

    const __hip_bfloat16* asrc0 = Xb + (size_t)(brow + g_row) * K_TOT + g_col;
    const __hip_bfloat16* bsrc0 = Wb + (size_t)(bcol + g_row) * K_TOT + g_col;

    f32x4 acc[4][4];
#pragma unroll
    for (int m = 0; m < 4; ++m)
#pragma unroll
        for (int n = 0; n < 4; ++n)
#pragma unroll
            for (int i = 0; i < 4; ++i) acc[m][n][i] = 0.0f;

    for (int t = 0; t < NT; ++t) {
        const size_t k0 = (size_t)t * BK;
#pragma unroll
        for (int i = 0; i < 4; ++i) {
            gload16(asrc0 + k0 + (size_t)i * 8 * K_TOT, &As[wid * 2048 + i * 512]);
            gload16(bsrc0 + k0 + (size_t)i * 8 * K_TOT, &Bs[wid * 2048 + i * 512]);
        }
        __syncthreads();   // drains vmcnt(0): staged tile visible

#pragma unroll
        for (int kk = 0; kk < 2; ++kk) {
            short8 af[4], bfr[4];
#pragma unroll
            for (int m = 0; m < 4; ++m)
                af[m] = *(const short8*)(&As[(wr * 64 + m * 16 + lr) * BK + kk * 32 + kb * 8]);
#pragma unroll
            for (int n = 0; n < 4; ++n)
                bfr[n] = *(const short8*)(&Bs[(wc * 64 + n * 16 + lr) * BK + kk * 32 + kb * 8]);
#pragma unroll
            for (int m = 0; m < 4; ++m)
#pragma unroll
                for (int n = 0; n < 4; ++n)
                    acc[m][n] = __builtin_amdgcn_mfma_f32_16x16x32_bf16(af[m], bfr[n], acc[m][n], 0, 0, 0);
        }
        __syncthreads();   // before overwriting the single buffer
    }

    // epilogue: out = acc * scale + bias
    const float sc = scale[0];
    const int orow0 = brow + wr * 64;
    const int ocol0 = bcol + wc * 64;
    float bv[4];
#pragma unroll
    for (int n = 0; n < 4; ++n) bv[n] = bias[ocol0 + n * 16 + lr];
#pragma unroll
    for (int m = 0; m < 4; ++m) {
#pragma unroll
        for (int i = 0; i < 4; ++i) {
            int r = orow0 + m * 16 + kb * 4 + i;    // C/D: row=(lane>>4)*4+reg, col=lane&15
            size_t base = (size_t)r * N_TOT + ocol0;
#pragma unroll
            for (int n = 0; n < 4; ++n)
                out[base + n * 16 + lr] = acc[m][n][i] * sc + bv[n];
        }
    }
}

// ---------------- fallback (round-1 fused kernel) if ws too small ----------------
__device__ __forceinline__ unsigned long long pack4(float a, float b, float c, float d) {
    return (unsigned long long)f2bf(a)
         | ((unsigned long long)f2bf(b) << 16)
         | ((unsigned long long)f2bf(c) << 32)
         | ((unsigned long long)f2bf(d) << 48);
}

__global__ __launch_bounds__(256, 2)
void otf_linear_fused(const float* __restrict__ X, const int* __restrict__ W,
                      const float* __restrict__ scale, const float* __restrict__ bias,
                      float* __restrict__ out) {
    __shared__ __align__(16) unsigned char AsB[BM * BK * 2];
    __shared__ __align__(16) unsigned char BsB[BN * BK * 2];

    const int tid = threadIdx.x, lane = tid & 63, wid = tid >> 6;
    const int wr = wid >> 1, wc = wid & 1, lr = lane & 15, kb = lane >> 4;
    const int brow = blockIdx.y * BM, bcol = blockIdx.x * BN;
    const int srow = tid >> 4, sc4 = tid & 15;

    f32x4 areg[8];
    int4 breg[8];
    auto load_tiles = [&](int t) {
        const int k0 = t * BK;
#pragma unroll
        for (int p = 0; p < 8; ++p) {
            int row = p * 16 + srow;
            areg[p] = *(const f32x4*)(&X[(size_t)(brow + row) * K_TOT + k0 + sc4 * 4]);
            breg[p] = *(const int4*)(&W[(size_t)(bcol + row) * K_TOT + k0 + sc4 * 4]);
        }
    };
    auto store_tiles = [&]() {
#pragma unroll
        for (int p = 0; p < 8; ++p) {
            int row = p * 16 + srow;
            int boff = (sc4 * 8) ^ ((row & 7) << 4);
            *(unsigned long long*)(&AsB[row * 128 + boff]) =
                pack4(areg[p][0], areg[p][1], areg[p][2], areg[p][3]);
            *(unsigned long long*)(&BsB[row * 128 + boff]) =
                pack4((float)breg[p].x, (float)breg[p].y, (float)breg[p].z, (float)breg[p].w);
        }
    };

    f32x4 acc[4][4];
#pragma unroll
    for (int m = 0; m < 4; ++m)
#pragma unroll
        for (int n = 0; n < 4; ++n)
#pragma unroll
            for (int i = 0; i < 4; ++i) acc[m][n][i] = 0.0f;

    load_tiles(0);
    for (int t = 0; t < NT; ++t) {
        store_tiles();
        __syncthreads();
        if (t + 1 < NT) load_tiles(t + 1);
#pragma unroll
        for (int kk = 0; kk < 2; ++kk) {
            short8 af[4], bfr[4];
#pragma unroll
            for (int m = 0; m < 4; ++m) {
                int row = wr * 64 + m * 16 + lr;
                int col = (kk * 64 + kb * 16) ^ ((row & 7) << 4);
                af[m] = *(const short8*)(&AsB[row * 128 + col]);
            }
#pragma unroll
            for (int n = 0; n < 4; ++n) {
                int row = wc * 64 + n * 16 + lr;
                int col = (kk * 64 + kb * 16) ^ ((row & 7) << 4);
                bfr[n] = *(const short8*)(&BsB[row * 128 + col]);
            }
#pragma unroll
            for (int m = 0; m < 4; ++m)
#pragma unroll
                for (int n = 0; n < 4; ++n)
                    acc[m][n] = __builtin_amdgcn_mfma_f32_16x16x32_bf16(af[m], bfr[n], acc[m][n], 0, 0, 0);
        }
        __syncthreads();
    }

    const float sc = scale[0];
    const int orow0 = brow + wr * 64, ocol0 = bcol + wc * 64;
    float bv[4];
#pragma unroll
    for (int n = 0; n < 4; ++n) bv[n] = bias[ocol0 + n * 16 + lr];
#pragma unroll
    for (int m = 0; m < 4; ++m)
#pragma unroll
        for (int i = 0; i < 4; ++i) {
            int r = orow0 + m * 16 + kb * 4 + i;
            size_t base = (size_t)r * N_TOT + ocol0;
#pragma unroll
            for (int n = 0; n < 4; ++n)
                out[base + n * 16 + lr] = acc[m][n][i] * sc + bv[n];
        }
}

extern "C" void kernel_launch(void* const* d_in, const int* in_sizes, int n_in,
                              void* d_out, int out_size, void* d_ws, size_t ws_size,
                              hipStream_t stream) {
    const float* x     = (const float*)d_in[0];
    const int*   w     = (const int*)d_in[1];
    const float* scale = (const float*)d_in[2];
    const float* bias  = (const float*)d_in[3];
    float* out = (float*)d_out;

    const size_t W_ELEMS = (size_t)N_TOT * K_TOT;   // 45,088,768
    const size_t X_ELEMS = (size_t)M_TOT * K_TOT;   //  4,194,304
    const size_t need = (W_ELEMS + X_ELEMS) * sizeof(__hip_bfloat16);  // ~94 MB

    if (ws_size >= need) {
        __hip_bfloat16* Wb = (__hip_bfloat16*)d_ws;
        __hip_bfloat16* Xb = (__hip_bfloat16*)((char*)d_ws + W_ELEMS * 2);
        conv_w_kernel<<<2048, 256, 0, stream>>>(w, Wb, (int)(W_ELEMS / 8));
        conv_x_kernel<<<2048, 256, 0, stream>>>(x, Xb, (int)(X_ELEMS / 8));
        gemm_bf16_kernel<<<dim3(N_TOT / BN, M_TOT / BM), 256, 0, stream>>>(Xb, Wb, scale, bias, out);
    } else {
        otf_linear_fused<<<dim3(N_TOT / BN, M_TOT / BM), 256, 0, stream>>>(x, w, scale, bias, out);
    }
}

// Round 3
// 152.527 us; speedup vs baseline: 1.7022x; 1.1719x over previous
//
#include <hip/hip_runtime.h>
#include <hip/hip_bf16.h>

// out[m,o] = sum_k x[m,k] * (W[o,k]*scale) + bias[o]
// M=1024, K=4096, N=11008.
// Pre-pass: W(int32)->bf16, X(f32)->bf16 into d_ws (BW-bound, compulsory).
// GEMM: 256x256 tile, BK=64, 512 threads (8 waves, 2Mx4N, per-wave 128x64),
//       dbuf 128KB LDS, early-stage + 1 barrier/tile, T2 swizzle
//       (linear gload_lds dest + inverse-swizzled GLOBAL source + swizzled
//       ds_read), T5 setprio around MFMA cluster.

#define M_TOT 1024
#define N_TOT 11008
#define K_TOT 4096
#define BM 256
#define BN 256
#define BK 64
#define NT (K_TOT / BK)  // 64 K-steps
#define ABYTES (BM * BK * 2)          // 32 KB
#define BUFB   ((BM + BN) * BK * 2)   // 64 KB per buffer

typedef __attribute__((ext_vector_type(8))) short short8;   // 8 bf16
typedef __attribute__((ext_vector_type(4))) float f32x4;

__device__ __forceinline__ unsigned short f2bf(float f) {
    __hip_bfloat16 h = __float2bfloat16(f);  // RNE
    return __builtin_bit_cast(unsigned short, h);
}

__device__ __forceinline__ void gload16(const void* g, void* l) {
    __builtin_amdgcn_global_load_lds(
        (const __attribute__((address_space(1))) unsigned int*)g,
        (__attribute__((address_space(3))) unsigned int*)l,
        16, 0, 0);
}

// ---------------- pre-pass: W int32 -> bf16 (exact: |v|<=127) ----------------
__global__ void conv_w_kernel(const int* __restrict__ W,
                              __hip_bfloat16* __restrict__ Wb, int n8) {
    int idx = blockIdx.x * blockDim.x + threadIdx.x;
    int stride = gridDim.x * blockDim.x;
    for (int i = idx; i < n8; i += stride) {
        const int4* p = (const int4*)W + (size_t)i * 2;
        int4 a = p[0], b = p[1];
        short8 o;
        o[0] = (short)f2bf((float)a.x);
        o[1] = (short)f2bf((float)a.y);
        o[2] = (short)f2bf((float)a.z);
        o[3] = (short)f2bf((float)a.w);
        o[4] = (short)f2bf((float)b.x);
        o[5] = (short)f2bf((float)b.y);
        o[6] = (short)f2bf((float)b.z);
        o[7] = (short)f2bf((float)b.w);
        *(short8*)(Wb + (size_t)i * 8) = o;
    }
}

// ---------------- pre-pass: X f32 -> bf16 ----------------
__global__ void conv_x_kernel(const float* __restrict__ X,
                              __hip_bfloat16* __restrict__ Xb, int n8) {
    int idx = blockIdx.x * blockDim.x + threadIdx.x;
    int stride = gridDim.x * blockDim.x;
    for (int i = idx; i < n8; i += stride) {
        const f32x4* p = (const f32x4*)X + (size_t)i * 2;
        f32x4 a = p[0], b = p[1];
        short8 o;
        o[0] = (short)f2bf(a[0]);
        o[1] = (short)f2bf(a[1]);
        o[2] = (short)f2bf(a[2]);
        o[3] = (short)f2bf(a[3]);
        o[4] = (short)f2bf(b[0]);
        o[5] = (short)f2bf(b[1]);
        o[6] = (short)f2bf(b[2]);
        o[7] = (short)f2bf(b[3]);
        *(short8*)(Xb + (size_t)i * 8) = o;
    }
}

// ---------------- main GEMM: bf16 NT, 256^2 dbuf early-stage ----------------
__global__ __launch_bounds__(512, 2)
void gemm_bf16_kernel(const __hip_bfloat16* __restrict__ Xb,   // [1024,4096]
                      const __hip_bfloat16* __restrict__ Wb,   // [11008,4096]
                      const float* __restrict__ scale,
                      const float* __restrict__ bias,
                      float* __restrict__ out) {               // [1024,11008]
    // two buffers, each: A[256][64] bf16 (32KB) then B[256][64] bf16 (32KB)
    __shared__ __align__(16) unsigned char lds[2 * BUFB];      // 128 KB

    const int tid  = threadIdx.x;     // 0..511
    const int lane = tid & 63;
    const int wid  = tid >> 6;        // 0..7
    const int wr   = wid >> 2;        // 0..1  (128-row sub-tile)
    const int wc   = wid & 3;         // 0..3  (64-col sub-tile)
    const int lr   = lane & 15;
    const int kb   = lane >> 4;       // 0..3

    const int brow = blockIdx.y * BM;
    const int bcol = blockIdx.x * BN;

    // ---- staging geometry (global_load_lds, linear LDS dest) ----
    // Each wave stages 32 rows of A and 32 rows of B: 4 chunks of 8 rows,
    // 1KB per gload16 (64 lanes x 16B). Lane l -> row (l>>3), byte (l&7)*16.
    // T2: LDS holds SWIZZLED content. Read applies col ^ ((row&7)<<4); since
    // gload_lds dest is linear, we pre-swizzle the GLOBAL source column:
    // src col elems = ((l&7) ^ (l>>3)) * 8   (row&7 == l>>3 for 8-aligned chunks)
    const int s_row  = wid * 32 + (lane >> 3);            // +8 per chunk i
    const int s_cole = (((lane & 7) ^ (lane >> 3)) * 8);  // bf16 elems within row

    const __hip_bfloat16* asrc0 = Xb + (size_t)(brow + s_row) * K_TOT + s_cole;
    const __hip_bfloat16* bsrc0 = Wb + (size_t)(bcol + s_row) * K_TOT + s_cole;
    const int lds_row0 = wid * 32;   // first A/B row this wave stages

    auto stage = [&](int t, unsigned char* buf) {
        const size_t k0 = (size_t)t * BK;
#pragma unroll
        for (int i = 0; i < 4; ++i) {
            gload16(asrc0 + k0 + (size_t)i * 8 * K_TOT,
                    buf + (lds_row0 + i * 8) * 128);
            gload16(bsrc0 + k0 + (size_t)i * 8 * K_TOT,
                    buf + ABYTES + (lds_row0 + i * 8) * 128);
        }
    };

    f32x4 acc[8][4];
#pragma unroll
    for (int m = 0; m < 8; ++m)
#pragma unroll
        for (int n = 0; n < 4; ++n)
#pragma unroll
            for (int i = 0; i < 4; ++i) acc[m][n][i] = 0.0f;

    stage(0, lds);
    __syncthreads();

    for (int t = 0; t < NT; ++t) {
        unsigned char* cur = lds + (size_t)(t & 1) * BUFB;
        unsigned char* nxt = lds + (size_t)((t + 1) & 1) * BUFB;
        if (t + 1 < NT) stage(t + 1, nxt);   // in flight across the compute

#pragma unroll
        for (int kk = 0; kk < 2; ++kk) {
            short8 af[8], bfr[4];
            const int swz = (lr & 7) << 4;
            const int colb = (kk * 32 + kb * 8) * 2;
#pragma unroll
            for (int m = 0; m < 8; ++m) {
                int row = wr * 128 + m * 16 + lr;
                af[m] = *(const short8*)(cur + row * 128 + (colb ^ swz));
            }
#pragma unroll
            for (int n = 0; n < 4; ++n) {
                int row = wc * 64 + n * 16 + lr;
                bfr[n] = *(const short8*)(cur + ABYTES + row * 128 + (colb ^ swz));
            }
            __builtin_amdgcn_s_setprio(1);
#pragma unroll
            for (int m = 0; m < 8; ++m)
#pragma unroll
                for (int n = 0; n < 4; ++n)
                    acc[m][n] = __builtin_amdgcn_mfma_f32_16x16x32_bf16(af[m], bfr[n], acc[m][n], 0, 0, 0);
            __builtin_amdgcn_s_setprio(0);
        }
        __syncthreads();   // drains vmcnt(0): next tile staged; cur free to overwrite
    }

    // epilogue: out = acc * scale + bias
    const float sc = scale[0];
    const int orow0 = brow + wr * 128;
    const int ocol0 = bcol + wc * 64;
    float bv[4];
#pragma unroll
    for (int n = 0; n < 4; ++n) bv[n] = bias[ocol0 + n * 16 + lr];
#pragma unroll
    for (int m = 0; m < 8; ++m) {
#pragma unroll
        for (int i = 0; i < 4; ++i) {
            int r = orow0 + m * 16 + kb * 4 + i;   // C/D: row=(lane>>4)*4+reg, col=lane&15
            size_t base = (size_t)r * N_TOT + ocol0;
#pragma unroll
            for (int n = 0; n < 4; ++n)
                out[base + n * 16 + lr] = acc[m][n][i] * sc + bv[n];
        }
    }
}

// ---------------- fallback (round-1 fused kernel) if ws too small ----------------
__device__ __forceinline__ unsigned long long pack4(float a, float b, float c, float d) {
    return (unsigned long long)f2bf(a)
         | ((unsigned long long)f2bf(b) << 16)
         | ((unsigned long long)f2bf(c) << 32)
         | ((unsigned long long)f2bf(d) << 48);
}

#define FBM 128
#define FBN 128

__global__ __launch_bounds__(256, 2)
void otf_linear_fused(const float* __restrict__ X, const int* __restrict__ W,
                      const float* __restrict__ scale, const float* __restrict__ bias,
                      float* __restrict__ out) {
    __shared__ __align__(16) unsigned char AsB[FBM * BK * 2];
    __shared__ __align__(16) unsigned char BsB[FBN * BK * 2];

    const int tid = threadIdx.x, lane = tid & 63, wid = tid >> 6;
    const int wr = wid >> 1, wc = wid & 1, lr = lane & 15, kb = lane >> 4;
    const int brow = blockIdx.y * FBM, bcol = blockIdx.x * FBN;
    const int srow = tid >> 4, sc4 = tid & 15;

    f32x4 areg[8];
    int4 breg[8];
    auto load_tiles = [&](int t) {
        const int k0 = t * BK;
#pragma unroll
        for (int p = 0; p < 8; ++p) {
            int row = p * 16 + srow;
            areg[p] = *(const f32x4*)(&X[(size_t)(brow + row) * K_TOT + k0 + sc4 * 4]);
            breg[p] = *(const int4*)(&W[(size_t)(bcol + row) * K_TOT + k0 + sc4 * 4]);
        }
    };
    auto store_tiles = [&]() {
#pragma unroll
        for (int p = 0; p < 8; ++p) {
            int row = p * 16 + srow;
            int boff = (sc4 * 8) ^ ((row & 7) << 4);
            *(unsigned long long*)(&AsB[row * 128 + boff]) =
                pack4(areg[p][0], areg[p][1], areg[p][2], areg[p][3]);
            *(unsigned long long*)(&BsB[row * 128 + boff]) =
                pack4((float)breg[p].x, (float)breg[p].y, (float)breg[p].z, (float)breg[p].w);
        }
    };

    f32x4 acc[4][4];
#pragma unroll
    for (int m = 0; m < 4; ++m)
#pragma unroll
        for (int n = 0; n < 4; ++n)
#pragma unroll
            for (int i = 0; i < 4; ++i) acc[m][n][i] = 0.0f;

    load_tiles(0);
    for (int t = 0; t < NT; ++t) {
        store_tiles();
        __syncthreads();
        if (t + 1 < NT) load_tiles(t + 1);
#pragma unroll
        for (int kk = 0; kk < 2; ++kk) {
            short8 af[4], bfr[4];
#pragma unroll
            for (int m = 0; m < 4; ++m) {
                int row = wr * 64 + m * 16 + lr;
                int col = (kk * 64 + kb * 16) ^ ((row & 7) << 4);
                af[m] = *(const short8*)(&AsB[row * 128 + col]);
            }
#pragma unroll
            for (int n = 0; n < 4; ++n) {
                int row = wc * 64 + n * 16 + lr;
                int col = (kk * 64 + kb * 16) ^ ((row & 7) << 4);
                bfr[n] = *(const short8*)(&BsB[row * 128 + col]);
            }
#pragma unroll
            for (int m = 0; m < 4; ++m)
#pragma unroll
                for (int n = 0; n < 4; ++n)
                    acc[m][n] = __builtin_amdgcn_mfma_f32_16x16x32_bf16(af[m], bfr[n], acc[m][n], 0, 0, 0);
        }
        __syncthreads();
    }

    const float sc = scale[0];
    const int orow0 = brow + wr * 64, ocol0 = bcol + wc * 64;
    float bv[4];
#pragma unroll
    for (int n = 0; n < 4; ++n) bv[n] = bias[ocol0 + n * 16 + lr];
#pragma unroll
    for (int m = 0; m < 4; ++m)
#pragma unroll
        for (int i = 0; i < 4; ++i) {
            int r = orow0 + m * 16 + kb * 4 + i;
            size_t base = (size_t)r * N_TOT + ocol0;
#pragma unroll
            for (int n = 0; n < 4; ++n)
                out[base + n * 16 + lr] = acc[m][n][i] * sc + bv[n];
        }
}

extern "C" void kernel_launch(void* const* d_in, const int* in_sizes, int n_in,
                              void* d_out, int out_size, void* d_ws, size_t ws_size,
                              hipStream_t stream) {
    const float* x     = (const float*)d_in[0];
    const int*   w     = (const int*)d_in[1];
    const float* scale = (const float*)d_in[2];
    const float* bias  = (const float*)d_in[3];
    float* out = (float*)d_out;

    const size_t W_ELEMS = (size_t)N_TOT * K_TOT;   // 45,088,768
    const size_t X_ELEMS = (size_t)M_TOT * K_TOT;   //  4,194,304
    const size_t need = (W_ELEMS + X_ELEMS) * sizeof(__hip_bfloat16);  // ~94 MB

    if (ws_size >= need) {
        __hip_bfloat16* Wb = (__hip_bfloat16*)d_ws;
        __hip_bfloat16* Xb = (__hip_bfloat16*)((char*)d_ws + W_ELEMS * 2);
        conv_w_kernel<<<2048, 256, 0, stream>>>(w, Wb, (int)(W_ELEMS / 8));
        conv_x_kernel<<<2048, 256, 0, stream>>>(x, Xb, (int)(X_ELEMS / 8));
        gemm_bf16_kernel<<<dim3(N_TOT / BN, M_TOT / BM), 512, 0, stream>>>(Xb, Wb, scale, bias, out);
    } else {
        otf_linear_fused<<<dim3(N_TOT / FBN, M_TOT / FBM), 256, 0, stream>>>(x, w, scale, bias, out);
    }
}